// Round 1
// baseline (1301.957 us; speedup 1.0000x reference)
//
#include <hip/hip_runtime.h>
#include <math.h>

#define NN 50000
#define NE 800000
#define GG 50

typedef unsigned int u32;

// ---------------- utility ----------------
__global__ void zero_u32_kernel(u32* __restrict__ p, int n) {
    int i = blockIdx.x * 256 + threadIdx.x;
    if (i < n) p[i] = 0u;
}

// ---------------- CSR build (by dst) ----------------
__global__ void count_edges_kernel(const int* __restrict__ ei, u32* __restrict__ counts) {
    int e = blockIdx.x * 256 + threadIdx.x;
    if (e < NE) atomicAdd(&counts[ei[NE + e]], 1u);
}

__global__ void scan_part1_kernel(const u32* __restrict__ counts, u32* __restrict__ bsums) {
    __shared__ u32 ls[256];
    int t = threadIdx.x;
    int base = blockIdx.x * 1024 + t * 4;
    u32 s = 0;
#pragma unroll
    for (int j = 0; j < 4; ++j) { int idx = base + j; if (idx < NN) s += counts[idx]; }
    ls[t] = s;
    __syncthreads();
    for (int off = 128; off > 0; off >>= 1) {
        if (t < off) ls[t] += ls[t + off];
        __syncthreads();
    }
    if (t == 0) bsums[blockIdx.x] = ls[0];
}

__global__ void scan_offsets_kernel(u32* bsums, int nb) {
    if (threadIdx.x == 0 && blockIdx.x == 0) {
        u32 run = 0;
        for (int i = 0; i < nb; ++i) { u32 v = bsums[i]; bsums[i] = run; run += v; }
    }
}

__global__ void scan_final_kernel(const u32* __restrict__ counts, const u32* __restrict__ bsums,
                                  int* __restrict__ rowptr) {
    __shared__ u32 ls[256];
    int t = threadIdx.x;
    int base = blockIdx.x * 1024 + t * 4;
    u32 c[4];
    u32 s = 0;
#pragma unroll
    for (int j = 0; j < 4; ++j) { int idx = base + j; c[j] = (idx < NN) ? counts[idx] : 0u; s += c[j]; }
    ls[t] = s;
    __syncthreads();
    for (int off = 1; off < 256; off <<= 1) {
        u32 add = (t >= off) ? ls[t - off] : 0u;
        __syncthreads();
        ls[t] += add;
        __syncthreads();
    }
    u32 run = ls[t] - s + bsums[blockIdx.x];
#pragma unroll
    for (int j = 0; j < 4; ++j) { int idx = base + j; if (idx < NN) { rowptr[idx] = (int)run; } run += c[j]; }
    if (blockIdx.x == 0 && t == 0) rowptr[NN] = NE;
}

__global__ void scatter_edges_kernel(const int* __restrict__ ei, const int* __restrict__ rowptr,
                                     u32* __restrict__ cursors, int* __restrict__ eids) {
    int e = blockIdx.x * 256 + threadIdx.x;
    if (e < NE) {
        int d = ei[NE + e];
        u32 pos = atomicAdd(&cursors[d], 1u);
        eids[rowptr[d] + pos] = e;
    }
}

// ---------------- GEMM: C[n,M] = X[n,128] @ W[128,M] + b ; BM=BN=64 ----------------
__global__ __launch_bounds__(256) void gemm_bias_kernel(
    const float* __restrict__ X, const float* __restrict__ W, const float* __restrict__ b,
    float* __restrict__ C, int n, int M)
{
    __shared__ __align__(16) float Xs[128][68];  // [k][row], pad keeps 16B align + breaks conflicts
    __shared__ __align__(16) float Ws[128][64];  // [k][col]
    int t = threadIdx.x;
    int row0 = blockIdx.y * 64, col0 = blockIdx.x * 64;

    int kq = (t & 31) * 4;
#pragma unroll
    for (int i = 0; i < 8; ++i) {
        int r = (t >> 5) + i * 8;
        int gr = row0 + r;
        float4 v = make_float4(0.f, 0.f, 0.f, 0.f);
        if (gr < n) v = *(const float4*)(X + (size_t)gr * 128 + kq);
        Xs[kq + 0][r] = v.x; Xs[kq + 1][r] = v.y; Xs[kq + 2][r] = v.z; Xs[kq + 3][r] = v.w;
    }
    int cq = (t & 15) * 4;
#pragma unroll
    for (int i = 0; i < 8; ++i) {
        int k = (t >> 4) + i * 16;
        *(float4*)&Ws[k][cq] = *(const float4*)(W + (size_t)k * M + col0 + cq);
    }
    __syncthreads();

    int tx = t & 15, ty = t >> 4;
    float acc[4][4] = {};
#pragma unroll 4
    for (int k = 0; k < 128; ++k) {
        float4 xv = *(const float4*)&Xs[k][ty * 4];
        float4 wv = *(const float4*)&Ws[k][tx * 4];
        float xa[4] = {xv.x, xv.y, xv.z, xv.w};
        float wa[4] = {wv.x, wv.y, wv.z, wv.w};
#pragma unroll
        for (int i = 0; i < 4; ++i)
#pragma unroll
            for (int j = 0; j < 4; ++j)
                acc[i][j] = fmaf(xa[i], wa[j], acc[i][j]);
    }
    float4 bb = *(const float4*)(b + col0 + tx * 4);
    float ba[4] = {bb.x, bb.y, bb.z, bb.w};
#pragma unroll
    for (int i = 0; i < 4; ++i) {
        int gr = row0 + ty * 4 + i;
        if (gr < n) {
            float4 o;
            o.x = acc[i][0] + ba[0]; o.y = acc[i][1] + ba[1];
            o.z = acc[i][2] + ba[2]; o.w = acc[i][3] + ba[3];
            *(float4*)(C + (size_t)gr * M + col0 + tx * 4) = o;
        }
    }
}

// ---------------- edge logits, layer 1 (H=2, C=64; wave per edge, grid-stride) ----------------
__global__ __launch_bounds__(256) void edge_logits1_kernel(
    const float* __restrict__ xl, const float* __restrict__ xr,
    const float* __restrict__ ea, const int* __restrict__ ei,
    const float* __restrict__ We, const float* __restrict__ att,
    float* __restrict__ logits)
{
    int lane = threadIdx.x & 63;
    int wid = (blockIdx.x * 256 + threadIdx.x) >> 6;
    int nw = (gridDim.x * 256) >> 6;
    int c0 = lane * 2;
    float2 w[16];
#pragma unroll
    for (int k = 0; k < 16; ++k) w[k] = *(const float2*)(We + k * 128 + c0);
    float a0 = att[c0], a1 = att[c0 + 1];
    for (int e = wid; e < NE; e += nw) {
        int src = ei[e], dst = ei[NE + e];
        float eav = ea[(size_t)e * 16 + (lane & 15)];
        float e0 = 0.f, e1 = 0.f;
#pragma unroll
        for (int k = 0; k < 16; ++k) {
            float aa = __shfl(eav, k, 64);
            e0 = fmaf(aa, w[k].x, e0);
            e1 = fmaf(aa, w[k].y, e1);
        }
        float2 xlv = *(const float2*)(xl + (size_t)src * 128 + c0);
        float2 xrv = *(const float2*)(xr + (size_t)dst * 128 + c0);
        float m0 = xlv.x + xrv.x + e0;
        float m1 = xlv.y + xrv.y + e1;
        m0 = (m0 > 0.f) ? m0 : 0.2f * m0;
        m1 = (m1 > 0.f) ? m1 : 0.2f * m1;
        float p = fmaf(m0, a0, m1 * a1);
#pragma unroll
        for (int off = 1; off <= 16; off <<= 1) p += __shfl_xor(p, off, 64);
        if (lane == 0) logits[e * 2] = p;          // head 0 = lanes 0..31 (ch 0..63)
        else if (lane == 32) logits[e * 2 + 1] = p; // head 1 = lanes 32..63 (ch 64..127)
    }
}

// ---------------- edge logits, layer 2 (H=1, C=64) ----------------
__global__ __launch_bounds__(256) void edge_logits2_kernel(
    const float* __restrict__ xl, const float* __restrict__ xr,
    const float* __restrict__ ea, const int* __restrict__ ei,
    const float* __restrict__ We, const float* __restrict__ att,
    float* __restrict__ logits)
{
    int lane = threadIdx.x & 63;
    int wid = (blockIdx.x * 256 + threadIdx.x) >> 6;
    int nw = (gridDim.x * 256) >> 6;
    float w[16];
#pragma unroll
    for (int k = 0; k < 16; ++k) w[k] = We[k * 64 + lane];
    float a0 = att[lane];
    for (int e = wid; e < NE; e += nw) {
        int src = ei[e], dst = ei[NE + e];
        float eav = ea[(size_t)e * 16 + (lane & 15)];
        float ec = 0.f;
#pragma unroll
        for (int k = 0; k < 16; ++k) ec = fmaf(__shfl(eav, k, 64), w[k], ec);
        float m = xl[(size_t)src * 64 + lane] + xr[(size_t)dst * 64 + lane] + ec;
        m = (m > 0.f) ? m : 0.2f * m;
        float p = m * a0;
#pragma unroll
        for (int off = 1; off <= 32; off <<= 1) p += __shfl_xor(p, off, 64);
        if (lane == 0) logits[e] = p;
    }
}

// ---------------- dst-parallel online-softmax aggregation, layer 1 ----------------
__global__ __launch_bounds__(256) void aggregate1_kernel(
    const float* __restrict__ xl, const float* __restrict__ logits,
    const int* __restrict__ ei, const int* __restrict__ rowptr,
    const int* __restrict__ eids, const float* __restrict__ bias,
    float* __restrict__ h1)
{
    int lane = threadIdx.x & 63;
    int d = (blockIdx.x * 256 + threadIdx.x) >> 6;
    if (d >= NN) return;
    int beg = rowptr[d], end = rowptr[d + 1];
    int c0 = lane * 2;
    bool h0 = (lane < 32);
    float m0 = -INFINITY, m1 = -INFINITY, s0 = 0.f, s1 = 0.f, a0 = 0.f, a1 = 0.f;
    for (int i = beg; i < end; ++i) {
        int e = eids[i];
        int src = ei[e];
        float2 lg = *(const float2*)(logits + (size_t)e * 2);
        float nm0 = fmaxf(m0, lg.x), nm1 = fmaxf(m1, lg.y);
        float r0 = __expf(m0 - nm0), r1 = __expf(m1 - nm1);
        float w0 = __expf(lg.x - nm0), w1 = __expf(lg.y - nm1);
        s0 = s0 * r0 + w0; s1 = s1 * r1 + w1;
        m0 = nm0; m1 = nm1;
        float rr = h0 ? r0 : r1;
        float ww = h0 ? w0 : w1;
        float2 xv = *(const float2*)(xl + (size_t)src * 128 + c0);
        a0 = a0 * rr + ww * xv.x;
        a1 = a1 * rr + ww * xv.y;
    }
    float inv = 1.f / ((h0 ? s0 : s1) + 1e-16f);
    float2 o;
    o.x = a0 * inv + bias[c0];
    o.y = a1 * inv + bias[c0 + 1];
    *(float2*)(h1 + (size_t)d * 128 + c0) = o;
}

// ---------------- aggregation, layer 2 (single head) ----------------
__global__ __launch_bounds__(256) void aggregate2_kernel(
    const float* __restrict__ xl, const float* __restrict__ logits,
    const int* __restrict__ ei, const int* __restrict__ rowptr,
    const int* __restrict__ eids, const float* __restrict__ bias,
    float* __restrict__ outp)
{
    int lane = threadIdx.x & 63;
    int d = (blockIdx.x * 256 + threadIdx.x) >> 6;
    if (d >= NN) return;
    int beg = rowptr[d], end = rowptr[d + 1];
    float m = -INFINITY, s = 0.f, a = 0.f;
    for (int i = beg; i < end; ++i) {
        int e = eids[i];
        int src = ei[e];
        float lg = logits[e];
        float nm = fmaxf(m, lg);
        float r = __expf(m - nm), w = __expf(lg - nm);
        s = s * r + w; m = nm;
        a = a * r + w * xl[(size_t)src * 64 + lane];
    }
    outp[(size_t)d * 64 + lane] = a / (s + 1e-16f) + bias[lane];
}

// ---------------- batch-norm stats (sum, sumsq per channel) ----------------
template <int C>
__global__ __launch_bounds__(256) void bn_stats_kernel(const float* __restrict__ h, float* __restrict__ stats) {
    const int SUB = 256 / C;
    int t = threadIdx.x;
    int c = t & (C - 1);
    int rs = t / C;
    int r0 = blockIdx.x * 512;
    int r1 = min(NN, r0 + 512);
    float s = 0.f, s2 = 0.f;
    for (int r = r0 + rs; r < r1; r += SUB) {
        float v = h[(size_t)r * C + c];
        s += v; s2 = fmaf(v, v, s2);
    }
    __shared__ float ls[256], ls2[256];
    ls[t] = s; ls2[t] = s2;
    __syncthreads();
    if (rs == 0) {
        for (int j = 1; j < SUB; ++j) { s += ls[j * C + c]; s2 += ls2[j * C + c]; }
        atomicAdd(&stats[c], s);
        atomicAdd(&stats[C + c], s2);
    }
}

// ---------------- BN apply + skip + ELU ----------------
template <int C>
__global__ __launch_bounds__(256) void bn_apply_kernel(
    const float* __restrict__ h, const float* __restrict__ xp,
    const float* __restrict__ stats, const float* __restrict__ g,
    const float* __restrict__ b, float* __restrict__ outp)
{
    int i = blockIdx.x * 256 + threadIdx.x;
    if (i >= NN * C) return;
    int c = i & (C - 1);
    float mu = stats[c] * (1.f / NN);
    float var = stats[C + c] * (1.f / NN) - mu * mu;
    float sc = rsqrtf(var + 1e-5f) * g[c];
    float v = (h[i] - mu) * sc + b[c] + xp[i];
    outp[i] = (v > 0.f) ? v : expm1f(v);
}

// ---------------- per-graph mean/max pooling ----------------
__global__ __launch_bounds__(256) void pool_kernel(
    const float* __restrict__ h2, const int* __restrict__ batch, float* __restrict__ pooled)
{
    int g = blockIdx.x;
    int t = threadIdx.x;
    int lane = t & 63, w = t >> 6;
    int lo = 0, hi = NN;
    while (lo < hi) { int mid = (lo + hi) >> 1; if (batch[mid] < g) lo = mid + 1; else hi = mid; }
    int s0 = lo;
    hi = NN;
    while (lo < hi) { int mid = (lo + hi) >> 1; if (batch[mid] < g + 1) lo = mid + 1; else hi = mid; }
    int e0 = lo;
    float sum = 0.f, mx = -INFINITY;
    for (int r = s0 + w; r < e0; r += 4) {
        float v = h2[(size_t)r * 64 + lane];
        sum += v; mx = fmaxf(mx, v);
    }
    __shared__ float lsum[256], lmax[256];
    lsum[t] = sum; lmax[t] = mx;
    __syncthreads();
    if (w == 0) {
        for (int j = 1; j < 4; ++j) { sum += lsum[j * 64 + lane]; mx = fmaxf(mx, lmax[j * 64 + lane]); }
        float cnt = (float)(e0 - s0);
        pooled[g * 128 + lane] = sum / fmaxf(cnt, 1.f);
        pooled[g * 128 + 64 + lane] = mx;
    }
}

// ---------------- classifier ----------------
__global__ void classifier_kernel(const float* __restrict__ pooled, const float* __restrict__ w,
                                  const float* __restrict__ b, float* __restrict__ outp)
{
    int t = threadIdx.x;
    if (t < 100) {
        int g = t >> 1, c = t & 1;
        float acc = b[c];
        for (int k = 0; k < 128; ++k) acc = fmaf(pooled[g * 128 + k], w[k * 2 + c], acc);
        outp[t] = acc;
    }
}

extern "C" void kernel_launch(void* const* d_in, const int* in_sizes, int n_in,
                              void* d_out, int out_size, void* d_ws, size_t ws_size,
                              hipStream_t stream)
{
    const float* x       = (const float*)d_in[0];
    const int*   ei      = (const int*)d_in[1];
    const float* ea      = (const float*)d_in[2];
    const int*   batch   = (const int*)d_in[3];
    const float* skip1_w = (const float*)d_in[4];
    const float* skip1_b = (const float*)d_in[5];
    const float* c1_wl   = (const float*)d_in[6];
    const float* c1_bl   = (const float*)d_in[7];
    const float* c1_wr   = (const float*)d_in[8];
    const float* c1_br   = (const float*)d_in[9];
    const float* c1_we   = (const float*)d_in[10];
    const float* c1_att  = (const float*)d_in[11];
    const float* c1_bias = (const float*)d_in[12];
    const float* bn1_g   = (const float*)d_in[13];
    const float* bn1_b   = (const float*)d_in[14];
    const float* skip2_w = (const float*)d_in[15];
    const float* skip2_b = (const float*)d_in[16];
    const float* c2_wl   = (const float*)d_in[17];
    const float* c2_bl   = (const float*)d_in[18];
    const float* c2_wr   = (const float*)d_in[19];
    const float* c2_br   = (const float*)d_in[20];
    const float* c2_we   = (const float*)d_in[21];
    const float* c2_att  = (const float*)d_in[22];
    const float* c2_bias = (const float*)d_in[23];
    const float* bn2_g   = (const float*)d_in[24];
    const float* bn2_b   = (const float*)d_in[25];
    const float* cls_w   = (const float*)d_in[26];
    const float* cls_b   = (const float*)d_in[27];
    float* outp = (float*)d_out;

    // workspace layout (floats), with aliasing across phases
    float* ws = (float*)d_ws;
    size_t o = 0;
    float* A   = ws + o; o += 6400000;   // xl1 ; later xl2 (lower 3.2M) + xr2 (upper 3.2M)
    float* B   = ws + o; o += 6400000;   // xr1 ; later h (post-layer1 activations)
    float* Cb  = ws + o; o += 6400000;   // xp1 ; later xp2 (lower) + h2 (upper)
    float* D   = ws + o; o += 6400000;   // h1  ; later h2acc
    float* LOG = ws + o; o += 1600000;   // logits1 [E,2] ; later logits2 [E]
    int*   EIDS = (int*)(ws + o); o += 800000;
    u32*   COUNTS  = (u32*)(ws + o); o += 50000;   // --- zeroed region start
    u32*   CURSORS = (u32*)(ws + o); o += 50000;
    float* STATS1  = ws + o; o += 256;
    float* STATS2  = ws + o; o += 128;             // --- zeroed region = 100384 u32
    int*   ROWPTR  = (int*)(ws + o); o += 50016;
    u32*   BSUMS   = (u32*)(ws + o); o += 64;
    float* POOLED  = ws + o; o += 6400;

    float* xl2 = A;
    float* xr2 = A + 3200000;
    float* xp2 = Cb;
    float* h2  = Cb + 3200000;

    // zero counts/cursors/bn-stats (one contiguous region)
    zero_u32_kernel<<<(100384 + 255) / 256, 256, 0, stream>>>(COUNTS, 100384);

    // CSR by dst (shared by both layers)
    count_edges_kernel<<<(NE + 255) / 256, 256, 0, stream>>>(ei, COUNTS);
    scan_part1_kernel<<<49, 256, 0, stream>>>(COUNTS, BSUMS);
    scan_offsets_kernel<<<1, 64, 0, stream>>>(BSUMS, 49);
    scan_final_kernel<<<49, 256, 0, stream>>>(COUNTS, BSUMS, ROWPTR);
    scatter_edges_kernel<<<(NE + 255) / 256, 256, 0, stream>>>(ei, ROWPTR, CURSORS, EIDS);

    // ---- layer 1 ----
    dim3 g1(2, 782);
    gemm_bias_kernel<<<g1, 256, 0, stream>>>(x, c1_wl, c1_bl, A, NN, 128);   // xl1
    gemm_bias_kernel<<<g1, 256, 0, stream>>>(x, c1_wr, c1_br, B, NN, 128);   // xr1
    gemm_bias_kernel<<<g1, 256, 0, stream>>>(x, skip1_w, skip1_b, Cb, NN, 128); // xp1
    edge_logits1_kernel<<<2048, 256, 0, stream>>>(A, B, ea, ei, c1_we, c1_att, LOG);
    aggregate1_kernel<<<NN / 4, 256, 0, stream>>>(A, LOG, ei, ROWPTR, EIDS, c1_bias, D);
    bn_stats_kernel<128><<<98, 256, 0, stream>>>(D, STATS1);
    bn_apply_kernel<128><<<(NN * 128 + 255) / 256, 256, 0, stream>>>(D, Cb, STATS1, bn1_g, bn1_b, B);

    // ---- layer 2 ----
    dim3 g2(1, 782);
    gemm_bias_kernel<<<g2, 256, 0, stream>>>(B, c2_wl, c2_bl, xl2, NN, 64);
    gemm_bias_kernel<<<g2, 256, 0, stream>>>(B, c2_wr, c2_br, xr2, NN, 64);
    gemm_bias_kernel<<<g2, 256, 0, stream>>>(B, skip2_w, skip2_b, xp2, NN, 64);
    edge_logits2_kernel<<<2048, 256, 0, stream>>>(xl2, xr2, ea, ei, c2_we, c2_att, LOG);
    aggregate2_kernel<<<NN / 4, 256, 0, stream>>>(xl2, LOG, ei, ROWPTR, EIDS, c2_bias, D);
    bn_stats_kernel<64><<<98, 256, 0, stream>>>(D, STATS2);
    bn_apply_kernel<64><<<(NN * 64 + 255) / 256, 256, 0, stream>>>(D, xp2, STATS2, bn2_g, bn2_b, h2);

    // ---- pool + classify ----
    pool_kernel<<<GG, 256, 0, stream>>>(h2, batch, POOLED);
    classifier_kernel<<<1, 128, 0, stream>>>(POOLED, cls_w, cls_b, outp);
}

// Round 2
// 809.090 us; speedup vs baseline: 1.6092x; 1.6092x over previous
//
#include <hip/hip_runtime.h>
#include <math.h>

#define NN 50000
#define NE 800000
#define GG 50

typedef unsigned int u32;

// ---------------- utility ----------------
__global__ void zero_u32_kernel(u32* __restrict__ p, int n) {
    int i = blockIdx.x * 256 + threadIdx.x;
    if (i < n) p[i] = 0u;
}

// ---------------- CSR build (by dst) ----------------
__global__ void count_edges_kernel(const int* __restrict__ ei, u32* __restrict__ counts) {
    int e = blockIdx.x * 256 + threadIdx.x;
    if (e < NE) atomicAdd(&counts[ei[NE + e]], 1u);
}

__global__ void scan_part1_kernel(const u32* __restrict__ counts, u32* __restrict__ bsums) {
    __shared__ u32 ls[256];
    int t = threadIdx.x;
    int base = blockIdx.x * 1024 + t * 4;
    u32 s = 0;
#pragma unroll
    for (int j = 0; j < 4; ++j) { int idx = base + j; if (idx < NN) s += counts[idx]; }
    ls[t] = s;
    __syncthreads();
    for (int off = 128; off > 0; off >>= 1) {
        if (t < off) ls[t] += ls[t + off];
        __syncthreads();
    }
    if (t == 0) bsums[blockIdx.x] = ls[0];
}

__global__ void scan_offsets_kernel(u32* bsums, int nb) {
    if (threadIdx.x == 0 && blockIdx.x == 0) {
        u32 run = 0;
        for (int i = 0; i < nb; ++i) { u32 v = bsums[i]; bsums[i] = run; run += v; }
    }
}

__global__ void scan_final_kernel(const u32* __restrict__ counts, const u32* __restrict__ bsums,
                                  int* __restrict__ rowptr) {
    __shared__ u32 ls[256];
    int t = threadIdx.x;
    int base = blockIdx.x * 1024 + t * 4;
    u32 c[4];
    u32 s = 0;
#pragma unroll
    for (int j = 0; j < 4; ++j) { int idx = base + j; c[j] = (idx < NN) ? counts[idx] : 0u; s += c[j]; }
    ls[t] = s;
    __syncthreads();
    for (int off = 1; off < 256; off <<= 1) {
        u32 add = (t >= off) ? ls[t - off] : 0u;
        __syncthreads();
        ls[t] += add;
        __syncthreads();
    }
    u32 run = ls[t] - s + bsums[blockIdx.x];
#pragma unroll
    for (int j = 0; j < 4; ++j) { int idx = base + j; if (idx < NN) { rowptr[idx] = (int)run; } run += c[j]; }
    if (blockIdx.x == 0 && t == 0) rowptr[NN] = NE;
}

// store (src, e) pairs in CSR order so the hot loop has one less dependent gather
__global__ void scatter_edges_kernel(const int* __restrict__ ei, const int* __restrict__ rowptr,
                                     u32* __restrict__ cursors, int2* __restrict__ pairs) {
    int e = blockIdx.x * 256 + threadIdx.x;
    if (e < NE) {
        int src = ei[e];
        int d = ei[NE + e];
        u32 pos = atomicAdd(&cursors[d], 1u);
        pairs[rowptr[d] + pos] = make_int2(src, e);
    }
}

// ---------------- fused triple-GEMM: C_i[n,M] = X[n,128] @ W_i[128,M] + b_i ----------------
// one row-tile of X staged to LDS once, reused for all 3*(M/64) weight-column tiles
__global__ __launch_bounds__(256) void gemm_multi_kernel(
    const float* __restrict__ X,
    const float* __restrict__ W0, const float* __restrict__ b0, float* __restrict__ C0,
    const float* __restrict__ W1, const float* __restrict__ b1, float* __restrict__ C1,
    const float* __restrict__ W2, const float* __restrict__ b2, float* __restrict__ C2,
    int n, int M)
{
    __shared__ __align__(16) float Xs[128][68];  // [k][row]
    __shared__ __align__(16) float Wsh[128][64]; // [k][col]
    int t = threadIdx.x;
    int row0 = blockIdx.x * 64;

    int kq = (t & 31) * 4;
#pragma unroll
    for (int i = 0; i < 8; ++i) {
        int r = (t >> 5) + i * 8;
        int gr = row0 + r;
        float4 v = make_float4(0.f, 0.f, 0.f, 0.f);
        if (gr < n) v = *(const float4*)(X + (size_t)gr * 128 + kq);
        Xs[kq + 0][r] = v.x; Xs[kq + 1][r] = v.y; Xs[kq + 2][r] = v.z; Xs[kq + 3][r] = v.w;
    }

    int ntiles = 3 * (M >> 6);
    int cpm = M >> 6;  // col tiles per matrix
    int tx = t & 15, ty = t >> 4;
    int cq = (t & 15) * 4;

    for (int tile = 0; tile < ntiles; ++tile) {
        int mat = tile / cpm;
        int col0 = (tile - mat * cpm) * 64;
        const float* W = (mat == 0) ? W0 : (mat == 1) ? W1 : W2;
        const float* b = (mat == 0) ? b0 : (mat == 1) ? b1 : b2;
        float* C = (mat == 0) ? C0 : (mat == 1) ? C1 : C2;

        __syncthreads();  // Xs ready (first iter) / prev compute done before Wsh overwrite
#pragma unroll
        for (int i = 0; i < 8; ++i) {
            int k = (t >> 4) + i * 16;
            *(float4*)&Wsh[k][cq] = *(const float4*)(W + (size_t)k * M + col0 + cq);
        }
        __syncthreads();

        float acc[4][4] = {};
#pragma unroll 4
        for (int k = 0; k < 128; ++k) {
            float4 xv = *(const float4*)&Xs[k][ty * 4];
            float4 wv = *(const float4*)&Wsh[k][tx * 4];
            float xa[4] = {xv.x, xv.y, xv.z, xv.w};
            float wa[4] = {wv.x, wv.y, wv.z, wv.w};
#pragma unroll
            for (int i = 0; i < 4; ++i)
#pragma unroll
                for (int j = 0; j < 4; ++j)
                    acc[i][j] = fmaf(xa[i], wa[j], acc[i][j]);
        }
        float4 bb = *(const float4*)(b + col0 + tx * 4);
        float ba[4] = {bb.x, bb.y, bb.z, bb.w};
#pragma unroll
        for (int i = 0; i < 4; ++i) {
            int gr = row0 + ty * 4 + i;
            if (gr < n) {
                float4 o;
                o.x = acc[i][0] + ba[0]; o.y = acc[i][1] + ba[1];
                o.z = acc[i][2] + ba[2]; o.w = acc[i][3] + ba[3];
                *(float4*)(C + (size_t)gr * M + col0 + tx * 4) = o;
            }
        }
    }
}

// ---------------- fused GATv2 layer 1: logits + online-softmax + aggregate (H=2, C=64) ----------------
// one wave per dst node; xr row loop-invariant; xl gathered ONCE per edge
__global__ __launch_bounds__(256) void gat1_fused_kernel(
    const float* __restrict__ xl, const float* __restrict__ xr,
    const float* __restrict__ ea, const int2* __restrict__ pairs,
    const int* __restrict__ rowptr, const float* __restrict__ We,
    const float* __restrict__ att, const float* __restrict__ bias,
    float* __restrict__ out)
{
    int lane = threadIdx.x & 63;
    int d = (blockIdx.x * 256 + threadIdx.x) >> 6;
    if (d >= NN) return;
    int du = __builtin_amdgcn_readfirstlane(d);
    int beg = rowptr[du], end = rowptr[du + 1];
    int c0 = lane * 2;
    float2 w[16];
#pragma unroll
    for (int k = 0; k < 16; ++k) w[k] = *(const float2*)(We + k * 128 + c0);
    float a0 = att[c0], a1 = att[c0 + 1];
    float2 bb = *(const float2*)(bias + c0);
    float2 xrv = *(const float2*)(xr + (size_t)du * 128 + c0);

    float m = -INFINITY, s = 0.f, acc0 = 0.f, acc1 = 0.f;
    int2 pr = (beg < end) ? pairs[beg] : make_int2(0, 0);
    for (int i = beg; i < end; ++i) {
        int src = pr.x, e = pr.y;
        const float* ear = ea + (size_t)e * 16;
        float eav[16];
#pragma unroll
        for (int k = 0; k < 16; ++k) eav[k] = ear[k];  // wave-uniform -> scalar loads
        float2 xlv = *(const float2*)(xl + (size_t)src * 128 + c0);
        int nx = (i + 1 < end) ? i + 1 : i;
        pr = pairs[nx];  // prefetch next pair
        float e0 = 0.f, e1 = 0.f;
#pragma unroll
        for (int k = 0; k < 16; ++k) {
            e0 = fmaf(eav[k], w[k].x, e0);
            e1 = fmaf(eav[k], w[k].y, e1);
        }
        float m0 = xlv.x + xrv.x + e0;
        float m1 = xlv.y + xrv.y + e1;
        m0 = (m0 > 0.f) ? m0 : 0.2f * m0;
        m1 = (m1 > 0.f) ? m1 : 0.2f * m1;
        float p = fmaf(m0, a0, m1 * a1);
#pragma unroll
        for (int off = 1; off <= 16; off <<= 1) p += __shfl_xor(p, off, 64);
        // lanes 0..31 now hold head-0 logit, lanes 32..63 head-1 logit (matches channel split)
        float nm = fmaxf(m, p);
        float r = __expf(m - nm), ww = __expf(p - nm);
        s = s * r + ww;
        acc0 = acc0 * r + ww * xlv.x;
        acc1 = acc1 * r + ww * xlv.y;
        m = nm;
    }
    float inv = 1.f / (s + 1e-16f);
    float2 o;
    o.x = fmaf(acc0, inv, bb.x);
    o.y = fmaf(acc1, inv, bb.y);
    *(float2*)(out + (size_t)d * 128 + c0) = o;
}

// ---------------- fused GATv2 layer 2 (H=1, C=64) ----------------
__global__ __launch_bounds__(256) void gat2_fused_kernel(
    const float* __restrict__ xl, const float* __restrict__ xr,
    const float* __restrict__ ea, const int2* __restrict__ pairs,
    const int* __restrict__ rowptr, const float* __restrict__ We,
    const float* __restrict__ att, const float* __restrict__ bias,
    float* __restrict__ out)
{
    int lane = threadIdx.x & 63;
    int d = (blockIdx.x * 256 + threadIdx.x) >> 6;
    if (d >= NN) return;
    int du = __builtin_amdgcn_readfirstlane(d);
    int beg = rowptr[du], end = rowptr[du + 1];
    float w[16];
#pragma unroll
    for (int k = 0; k < 16; ++k) w[k] = We[k * 64 + lane];
    float a0 = att[lane];
    float bb = bias[lane];
    float xrv = xr[(size_t)du * 64 + lane];

    float m = -INFINITY, s = 0.f, acc = 0.f;
    int2 pr = (beg < end) ? pairs[beg] : make_int2(0, 0);
    for (int i = beg; i < end; ++i) {
        int src = pr.x, e = pr.y;
        const float* ear = ea + (size_t)e * 16;
        float eav[16];
#pragma unroll
        for (int k = 0; k < 16; ++k) eav[k] = ear[k];
        float xlv = xl[(size_t)src * 64 + lane];
        int nx = (i + 1 < end) ? i + 1 : i;
        pr = pairs[nx];
        float ec = 0.f;
#pragma unroll
        for (int k = 0; k < 16; ++k) ec = fmaf(eav[k], w[k], ec);
        float mm = xlv + xrv + ec;
        mm = (mm > 0.f) ? mm : 0.2f * mm;
        float p = mm * a0;
#pragma unroll
        for (int off = 1; off <= 32; off <<= 1) p += __shfl_xor(p, off, 64);
        float nm = fmaxf(m, p);
        float r = __expf(m - nm), ww = __expf(p - nm);
        s = s * r + ww;
        acc = acc * r + ww * xlv;
        m = nm;
    }
    out[(size_t)d * 64 + lane] = acc / (s + 1e-16f) + bb;
}

// ---------------- batch-norm stats (sum, sumsq per channel) ----------------
template <int C>
__global__ __launch_bounds__(256) void bn_stats_kernel(const float* __restrict__ h, float* __restrict__ stats) {
    const int SUB = 256 / C;
    int t = threadIdx.x;
    int c = t & (C - 1);
    int rs = t / C;
    int r0 = blockIdx.x * 512;
    int r1 = min(NN, r0 + 512);
    float s = 0.f, s2 = 0.f;
    for (int r = r0 + rs; r < r1; r += SUB) {
        float v = h[(size_t)r * C + c];
        s += v; s2 = fmaf(v, v, s2);
    }
    __shared__ float ls[256], ls2[256];
    ls[t] = s; ls2[t] = s2;
    __syncthreads();
    if (rs == 0) {
        for (int j = 1; j < SUB; ++j) { s += ls[j * C + c]; s2 += ls2[j * C + c]; }
        atomicAdd(&stats[c], s);
        atomicAdd(&stats[C + c], s2);
    }
}

// ---------------- BN apply + skip + ELU ----------------
template <int C>
__global__ __launch_bounds__(256) void bn_apply_kernel(
    const float* __restrict__ h, const float* __restrict__ xp,
    const float* __restrict__ stats, const float* __restrict__ g,
    const float* __restrict__ b, float* __restrict__ outp)
{
    int i = blockIdx.x * 256 + threadIdx.x;
    if (i >= NN * C) return;
    int c = i & (C - 1);
    float mu = stats[c] * (1.f / NN);
    float var = stats[C + c] * (1.f / NN) - mu * mu;
    float sc = rsqrtf(var + 1e-5f) * g[c];
    float v = (h[i] - mu) * sc + b[c] + xp[i];
    outp[i] = (v > 0.f) ? v : expm1f(v);
}

// ---------------- per-graph mean/max pooling ----------------
__global__ __launch_bounds__(256) void pool_kernel(
    const float* __restrict__ h2, const int* __restrict__ batch, float* __restrict__ pooled)
{
    int g = blockIdx.x;
    int t = threadIdx.x;
    int lane = t & 63, w = t >> 6;
    int lo = 0, hi = NN;
    while (lo < hi) { int mid = (lo + hi) >> 1; if (batch[mid] < g) lo = mid + 1; else hi = mid; }
    int s0 = lo;
    hi = NN;
    while (lo < hi) { int mid = (lo + hi) >> 1; if (batch[mid] < g + 1) lo = mid + 1; else hi = mid; }
    int e0 = lo;
    float sum = 0.f, mx = -INFINITY;
    for (int r = s0 + w; r < e0; r += 4) {
        float v = h2[(size_t)r * 64 + lane];
        sum += v; mx = fmaxf(mx, v);
    }
    __shared__ float lsum[256], lmax[256];
    lsum[t] = sum; lmax[t] = mx;
    __syncthreads();
    if (w == 0) {
        for (int j = 1; j < 4; ++j) { sum += lsum[j * 64 + lane]; mx = fmaxf(mx, lmax[j * 64 + lane]); }
        float cnt = (float)(e0 - s0);
        pooled[g * 128 + lane] = sum / fmaxf(cnt, 1.f);
        pooled[g * 128 + 64 + lane] = mx;
    }
}

// ---------------- classifier ----------------
__global__ void classifier_kernel(const float* __restrict__ pooled, const float* __restrict__ w,
                                  const float* __restrict__ b, float* __restrict__ outp)
{
    int t = threadIdx.x;
    if (t < 100) {
        int g = t >> 1, c = t & 1;
        float acc = b[c];
        for (int k = 0; k < 128; ++k) acc = fmaf(pooled[g * 128 + k], w[k * 2 + c], acc);
        outp[t] = acc;
    }
}

extern "C" void kernel_launch(void* const* d_in, const int* in_sizes, int n_in,
                              void* d_out, int out_size, void* d_ws, size_t ws_size,
                              hipStream_t stream)
{
    const float* x       = (const float*)d_in[0];
    const int*   ei      = (const int*)d_in[1];
    const float* ea      = (const float*)d_in[2];
    const int*   batch   = (const int*)d_in[3];
    const float* skip1_w = (const float*)d_in[4];
    const float* skip1_b = (const float*)d_in[5];
    const float* c1_wl   = (const float*)d_in[6];
    const float* c1_bl   = (const float*)d_in[7];
    const float* c1_wr   = (const float*)d_in[8];
    const float* c1_br   = (const float*)d_in[9];
    const float* c1_we   = (const float*)d_in[10];
    const float* c1_att  = (const float*)d_in[11];
    const float* c1_bias = (const float*)d_in[12];
    const float* bn1_g   = (const float*)d_in[13];
    const float* bn1_b   = (const float*)d_in[14];
    const float* skip2_w = (const float*)d_in[15];
    const float* skip2_b = (const float*)d_in[16];
    const float* c2_wl   = (const float*)d_in[17];
    const float* c2_bl   = (const float*)d_in[18];
    const float* c2_wr   = (const float*)d_in[19];
    const float* c2_br   = (const float*)d_in[20];
    const float* c2_we   = (const float*)d_in[21];
    const float* c2_att  = (const float*)d_in[22];
    const float* c2_bias = (const float*)d_in[23];
    const float* bn2_g   = (const float*)d_in[24];
    const float* bn2_b   = (const float*)d_in[25];
    const float* cls_w   = (const float*)d_in[26];
    const float* cls_b   = (const float*)d_in[27];
    float* outp = (float*)d_out;

    // workspace layout (floats)
    float* ws = (float*)d_ws;
    size_t o = 0;
    float* A   = ws + o; o += 6400000;   // xl1 ; later xl2 (lower 3.2M) + xr2 (upper 3.2M)
    float* B   = ws + o; o += 6400000;   // xr1 ; later h (post-layer1 activations)
    float* Cb  = ws + o; o += 6400000;   // xp1 ; later xp2 (lower) + h2 (upper)
    float* D   = ws + o; o += 6400000;   // h1  ; later h2 pre-BN
    int2*  PAIRS = (int2*)(ws + o); o += 1600000;  // (src, e) in CSR-by-dst order
    u32*   COUNTS  = (u32*)(ws + o); o += 50000;   // --- zeroed region start
    u32*   CURSORS = (u32*)(ws + o); o += 50000;
    float* STATS1  = ws + o; o += 256;
    float* STATS2  = ws + o; o += 128;             // --- zeroed region = 100384 u32
    int*   ROWPTR  = (int*)(ws + o); o += 50016;
    u32*   BSUMS   = (u32*)(ws + o); o += 64;
    float* POOLED  = ws + o; o += 6400;

    float* xl2 = A;
    float* xr2 = A + 3200000;
    float* xp2 = Cb;
    float* h2  = Cb + 3200000;

    // zero counts/cursors/bn-stats (one contiguous region)
    zero_u32_kernel<<<(100384 + 255) / 256, 256, 0, stream>>>(COUNTS, 100384);

    // CSR by dst (shared by both layers)
    count_edges_kernel<<<(NE + 255) / 256, 256, 0, stream>>>(ei, COUNTS);
    scan_part1_kernel<<<49, 256, 0, stream>>>(COUNTS, BSUMS);
    scan_offsets_kernel<<<1, 64, 0, stream>>>(BSUMS, 49);
    scan_final_kernel<<<49, 256, 0, stream>>>(COUNTS, BSUMS, ROWPTR);
    scatter_edges_kernel<<<(NE + 255) / 256, 256, 0, stream>>>(ei, ROWPTR, CURSORS, PAIRS);

    // ---- layer 1 ----
    gemm_multi_kernel<<<782, 256, 0, stream>>>(x,
        c1_wl, c1_bl, A,      // xl1
        c1_wr, c1_br, B,      // xr1
        skip1_w, skip1_b, Cb, // xp1
        NN, 128);
    gat1_fused_kernel<<<NN / 4, 256, 0, stream>>>(A, B, ea, PAIRS, ROWPTR, c1_we, c1_att, c1_bias, D);
    bn_stats_kernel<128><<<98, 256, 0, stream>>>(D, STATS1);
    bn_apply_kernel<128><<<(NN * 128 + 255) / 256, 256, 0, stream>>>(D, Cb, STATS1, bn1_g, bn1_b, B);

    // ---- layer 2 ----
    gemm_multi_kernel<<<782, 256, 0, stream>>>(B,
        c2_wl, c2_bl, xl2,
        c2_wr, c2_br, xr2,
        skip2_w, skip2_b, xp2,
        NN, 64);
    gat2_fused_kernel<<<NN / 4, 256, 0, stream>>>(xl2, xr2, ea, PAIRS, ROWPTR, c2_we, c2_att, c2_bias, D);
    bn_stats_kernel<64><<<98, 256, 0, stream>>>(D, STATS2);
    bn_apply_kernel<64><<<(NN * 64 + 255) / 256, 256, 0, stream>>>(D, xp2, STATS2, bn2_g, bn2_b, h2);

    // ---- pool + classify ----
    pool_kernel<<<GG, 256, 0, stream>>>(h2, batch, POOLED);
    classifier_kernel<<<1, 128, 0, stream>>>(POOLED, cls_w, cls_b, outp);
}

// Round 3
// 760.334 us; speedup vs baseline: 1.7123x; 1.0641x over previous
//
#include <hip/hip_runtime.h>
#include <math.h>

#define NN 50000
#define NE 800000
#define GG 50

typedef unsigned int u32;

// ---------------- utility ----------------
__global__ void zero_u32_kernel(u32* __restrict__ p, int n) {
    int i = blockIdx.x * 256 + threadIdx.x;
    if (i < n) p[i] = 0u;
}

// ---------------- CSR build (by dst) ----------------
__global__ void count_edges_kernel(const int* __restrict__ ei, u32* __restrict__ counts) {
    int e = blockIdx.x * 256 + threadIdx.x;
    if (e < NE) atomicAdd(&counts[ei[NE + e]], 1u);
}

__global__ void scan_part1_kernel(const u32* __restrict__ counts, u32* __restrict__ bsums) {
    __shared__ u32 ls[256];
    int t = threadIdx.x;
    int base = blockIdx.x * 1024 + t * 4;
    u32 s = 0;
#pragma unroll
    for (int j = 0; j < 4; ++j) { int idx = base + j; if (idx < NN) s += counts[idx]; }
    ls[t] = s;
    __syncthreads();
    for (int off = 128; off > 0; off >>= 1) {
        if (t < off) ls[t] += ls[t + off];
        __syncthreads();
    }
    if (t == 0) bsums[blockIdx.x] = ls[0];
}

// single-wave exclusive scan over <=64 block sums (was a 49-iter serial loop)
__global__ void scan_offsets_kernel(u32* bsums, int nb) {
    int lane = threadIdx.x;
    u32 v = (lane < nb) ? bsums[lane] : 0u;
#pragma unroll
    for (int off = 1; off < 64; off <<= 1) {
        u32 t = __shfl_up(v, off, 64);
        if (lane >= off) v += t;
    }
    u32 ex = __shfl_up(v, 1, 64);
    if (lane == 0) ex = 0u;
    if (lane < nb) bsums[lane] = ex;
}

__global__ void scan_final_kernel(const u32* __restrict__ counts, const u32* __restrict__ bsums,
                                  int* __restrict__ rowptr) {
    __shared__ u32 ls[256];
    int t = threadIdx.x;
    int base = blockIdx.x * 1024 + t * 4;
    u32 c[4];
    u32 s = 0;
#pragma unroll
    for (int j = 0; j < 4; ++j) { int idx = base + j; c[j] = (idx < NN) ? counts[idx] : 0u; s += c[j]; }
    ls[t] = s;
    __syncthreads();
    for (int off = 1; off < 256; off <<= 1) {
        u32 add = (t >= off) ? ls[t - off] : 0u;
        __syncthreads();
        ls[t] += add;
        __syncthreads();
    }
    u32 run = ls[t] - s + bsums[blockIdx.x];
#pragma unroll
    for (int j = 0; j < 4; ++j) { int idx = base + j; if (idx < NN) { rowptr[idx] = (int)run; } run += c[j]; }
    if (blockIdx.x == 0 && t == 0) rowptr[NN] = NE;
}

__global__ void scatter_edges_kernel(const int* __restrict__ ei, const int* __restrict__ rowptr,
                                     u32* __restrict__ cursors, int2* __restrict__ pairs) {
    int e = blockIdx.x * 256 + threadIdx.x;
    if (e < NE) {
        int src = ei[e];
        int d = ei[NE + e];
        u32 pos = atomicAdd(&cursors[d], 1u);
        pairs[rowptr[d] + pos] = make_int2(src, e);
    }
}

// ---------------- fused triple-GEMM ----------------
__global__ __launch_bounds__(256) void gemm_multi_kernel(
    const float* __restrict__ X,
    const float* __restrict__ W0, const float* __restrict__ b0, float* __restrict__ C0,
    const float* __restrict__ W1, const float* __restrict__ b1, float* __restrict__ C1,
    const float* __restrict__ W2, const float* __restrict__ b2, float* __restrict__ C2,
    int n, int M)
{
    __shared__ __align__(16) float Xs[128][68];
    __shared__ __align__(16) float Wsh[128][64];
    int t = threadIdx.x;
    int row0 = blockIdx.x * 64;

    int kq = (t & 31) * 4;
#pragma unroll
    for (int i = 0; i < 8; ++i) {
        int r = (t >> 5) + i * 8;
        int gr = row0 + r;
        float4 v = make_float4(0.f, 0.f, 0.f, 0.f);
        if (gr < n) v = *(const float4*)(X + (size_t)gr * 128 + kq);
        Xs[kq + 0][r] = v.x; Xs[kq + 1][r] = v.y; Xs[kq + 2][r] = v.z; Xs[kq + 3][r] = v.w;
    }

    int ntiles = 3 * (M >> 6);
    int cpm = M >> 6;
    int tx = t & 15, ty = t >> 4;
    int cq = (t & 15) * 4;

    for (int tile = 0; tile < ntiles; ++tile) {
        int mat = tile / cpm;
        int col0 = (tile - mat * cpm) * 64;
        const float* W = (mat == 0) ? W0 : (mat == 1) ? W1 : W2;
        const float* b = (mat == 0) ? b0 : (mat == 1) ? b1 : b2;
        float* C = (mat == 0) ? C0 : (mat == 1) ? C1 : C2;

        __syncthreads();
#pragma unroll
        for (int i = 0; i < 8; ++i) {
            int k = (t >> 4) + i * 16;
            *(float4*)&Wsh[k][cq] = *(const float4*)(W + (size_t)k * M + col0 + cq);
        }
        __syncthreads();

        float acc[4][4] = {};
#pragma unroll 4
        for (int k = 0; k < 128; ++k) {
            float4 xv = *(const float4*)&Xs[k][ty * 4];
            float4 wv = *(const float4*)&Wsh[k][tx * 4];
            float xa[4] = {xv.x, xv.y, xv.z, xv.w};
            float wa[4] = {wv.x, wv.y, wv.z, wv.w};
#pragma unroll
            for (int i = 0; i < 4; ++i)
#pragma unroll
                for (int j = 0; j < 4; ++j)
                    acc[i][j] = fmaf(xa[i], wa[j], acc[i][j]);
        }
        float4 bb = *(const float4*)(b + col0 + tx * 4);
        float ba[4] = {bb.x, bb.y, bb.z, bb.w};
#pragma unroll
        for (int i = 0; i < 4; ++i) {
            int gr = row0 + ty * 4 + i;
            if (gr < n) {
                float4 o;
                o.x = acc[i][0] + ba[0]; o.y = acc[i][1] + ba[1];
                o.z = acc[i][2] + ba[2]; o.w = acc[i][3] + ba[3];
                *(float4*)(C + (size_t)gr * M + col0 + tx * 4) = o;
            }
        }
    }
}

// ---------------- fused GATv2 layer 1 (H=2, C=64), edge loop unrolled x4 ----------------
__global__ __launch_bounds__(256) void gat1_fused_kernel(
    const float* __restrict__ xl, const float* __restrict__ xr,
    const float* __restrict__ ea, const int2* __restrict__ pairs,
    const int* __restrict__ rowptr, const float* __restrict__ We,
    const float* __restrict__ att, const float* __restrict__ bias,
    float* __restrict__ out)
{
    int lane = threadIdx.x & 63;
    int d = (blockIdx.x * 256 + threadIdx.x) >> 6;
    if (d >= NN) return;
    int du = __builtin_amdgcn_readfirstlane(d);
    int beg = rowptr[du], end = rowptr[du + 1];
    int c0 = lane * 2;
    float2 w[16];
#pragma unroll
    for (int k = 0; k < 16; ++k) w[k] = *(const float2*)(We + k * 128 + c0);
    float a0 = att[c0], a1 = att[c0 + 1];
    float2 bb = *(const float2*)(bias + c0);
    float2 xrv = *(const float2*)(xr + (size_t)du * 128 + c0);

    float m = -INFINITY, s = 0.f, acc0 = 0.f, acc1 = 0.f;

    int i = beg;
    for (; i + 4 <= end; i += 4) {
        int2 p0 = pairs[i], p1 = pairs[i + 1], p2 = pairs[i + 2], p3 = pairs[i + 3];
        // issue all gathers up front: 4 outstanding vmem + 4 scalar ea rows
        float2 x0 = *(const float2*)(xl + (size_t)p0.x * 128 + c0);
        float2 x1 = *(const float2*)(xl + (size_t)p1.x * 128 + c0);
        float2 x2 = *(const float2*)(xl + (size_t)p2.x * 128 + c0);
        float2 x3 = *(const float2*)(xl + (size_t)p3.x * 128 + c0);
        const float* er0 = ea + (size_t)p0.y * 16;
        const float* er1 = ea + (size_t)p1.y * 16;
        const float* er2 = ea + (size_t)p2.y * 16;
        const float* er3 = ea + (size_t)p3.y * 16;
        float e00 = 0.f, e01 = 0.f, e10 = 0.f, e11 = 0.f;
        float e20 = 0.f, e21 = 0.f, e30 = 0.f, e31 = 0.f;
#pragma unroll
        for (int k = 0; k < 16; ++k) {
            float a = er0[k], b2 = er1[k], c = er2[k], dd = er3[k];  // wave-uniform
            e00 = fmaf(a, w[k].x, e00);  e01 = fmaf(a, w[k].y, e01);
            e10 = fmaf(b2, w[k].x, e10); e11 = fmaf(b2, w[k].y, e11);
            e20 = fmaf(c, w[k].x, e20);  e21 = fmaf(c, w[k].y, e21);
            e30 = fmaf(dd, w[k].x, e30); e31 = fmaf(dd, w[k].y, e31);
        }
        float m00 = x0.x + xrv.x + e00, m01 = x0.y + xrv.y + e01;
        float m10 = x1.x + xrv.x + e10, m11 = x1.y + xrv.y + e11;
        float m20 = x2.x + xrv.x + e20, m21 = x2.y + xrv.y + e21;
        float m30 = x3.x + xrv.x + e30, m31 = x3.y + xrv.y + e31;
        m00 = (m00 > 0.f) ? m00 : 0.2f * m00;  m01 = (m01 > 0.f) ? m01 : 0.2f * m01;
        m10 = (m10 > 0.f) ? m10 : 0.2f * m10;  m11 = (m11 > 0.f) ? m11 : 0.2f * m11;
        m20 = (m20 > 0.f) ? m20 : 0.2f * m20;  m21 = (m21 > 0.f) ? m21 : 0.2f * m21;
        m30 = (m30 > 0.f) ? m30 : 0.2f * m30;  m31 = (m31 > 0.f) ? m31 : 0.2f * m31;
        float q0 = fmaf(m00, a0, m01 * a1);
        float q1 = fmaf(m10, a0, m11 * a1);
        float q2 = fmaf(m20, a0, m21 * a1);
        float q3 = fmaf(m30, a0, m31 * a1);
#pragma unroll
        for (int off = 1; off <= 16; off <<= 1) {
            q0 += __shfl_xor(q0, off, 64);
            q1 += __shfl_xor(q1, off, 64);
            q2 += __shfl_xor(q2, off, 64);
            q3 += __shfl_xor(q3, off, 64);
        }
        // batched online-softmax update (per-lane = its head's logit)
        float nm = fmaxf(fmaxf(fmaxf(q0, q1), fmaxf(q2, q3)), m);
        float r  = __expf(m - nm);
        float w0 = __expf(q0 - nm), w1 = __expf(q1 - nm);
        float w2 = __expf(q2 - nm), w3 = __expf(q3 - nm);
        s = fmaf(s, r, (w0 + w1) + (w2 + w3));
        acc0 = fmaf(acc0, r, fmaf(w0, x0.x, fmaf(w1, x1.x, fmaf(w2, x2.x, w3 * x3.x))));
        acc1 = fmaf(acc1, r, fmaf(w0, x0.y, fmaf(w1, x1.y, fmaf(w2, x2.y, w3 * x3.y))));
        m = nm;
    }
    for (; i < end; ++i) {
        int2 pr = pairs[i];
        const float* er = ea + (size_t)pr.y * 16;
        float2 xv = *(const float2*)(xl + (size_t)pr.x * 128 + c0);
        float e0 = 0.f, e1 = 0.f;
#pragma unroll
        for (int k = 0; k < 16; ++k) {
            float a = er[k];
            e0 = fmaf(a, w[k].x, e0);
            e1 = fmaf(a, w[k].y, e1);
        }
        float m0 = xv.x + xrv.x + e0;
        float m1 = xv.y + xrv.y + e1;
        m0 = (m0 > 0.f) ? m0 : 0.2f * m0;
        m1 = (m1 > 0.f) ? m1 : 0.2f * m1;
        float p = fmaf(m0, a0, m1 * a1);
#pragma unroll
        for (int off = 1; off <= 16; off <<= 1) p += __shfl_xor(p, off, 64);
        float nm = fmaxf(m, p);
        float r = __expf(m - nm), ww = __expf(p - nm);
        s = fmaf(s, r, ww);
        acc0 = fmaf(acc0, r, ww * xv.x);
        acc1 = fmaf(acc1, r, ww * xv.y);
        m = nm;
    }
    float inv = 1.f / (s + 1e-16f);
    float2 o;
    o.x = fmaf(acc0, inv, bb.x);
    o.y = fmaf(acc1, inv, bb.y);
    *(float2*)(out + (size_t)d * 128 + c0) = o;
}

// ---------------- fused GATv2 layer 2 (H=1, C=64), edge loop unrolled x4 ----------------
__global__ __launch_bounds__(256) void gat2_fused_kernel(
    const float* __restrict__ xl, const float* __restrict__ xr,
    const float* __restrict__ ea, const int2* __restrict__ pairs,
    const int* __restrict__ rowptr, const float* __restrict__ We,
    const float* __restrict__ att, const float* __restrict__ bias,
    float* __restrict__ out)
{
    int lane = threadIdx.x & 63;
    int d = (blockIdx.x * 256 + threadIdx.x) >> 6;
    if (d >= NN) return;
    int du = __builtin_amdgcn_readfirstlane(d);
    int beg = rowptr[du], end = rowptr[du + 1];
    float w[16];
#pragma unroll
    for (int k = 0; k < 16; ++k) w[k] = We[k * 64 + lane];
    float a0 = att[lane];
    float bb = bias[lane];
    float xrv = xr[(size_t)du * 64 + lane];

    float m = -INFINITY, s = 0.f, acc = 0.f;

    int i = beg;
    for (; i + 4 <= end; i += 4) {
        int2 p0 = pairs[i], p1 = pairs[i + 1], p2 = pairs[i + 2], p3 = pairs[i + 3];
        float x0 = xl[(size_t)p0.x * 64 + lane];
        float x1 = xl[(size_t)p1.x * 64 + lane];
        float x2 = xl[(size_t)p2.x * 64 + lane];
        float x3 = xl[(size_t)p3.x * 64 + lane];
        const float* er0 = ea + (size_t)p0.y * 16;
        const float* er1 = ea + (size_t)p1.y * 16;
        const float* er2 = ea + (size_t)p2.y * 16;
        const float* er3 = ea + (size_t)p3.y * 16;
        float e0 = 0.f, e1 = 0.f, e2 = 0.f, e3 = 0.f;
#pragma unroll
        for (int k = 0; k < 16; ++k) {
            e0 = fmaf(er0[k], w[k], e0);
            e1 = fmaf(er1[k], w[k], e1);
            e2 = fmaf(er2[k], w[k], e2);
            e3 = fmaf(er3[k], w[k], e3);
        }
        float m0 = x0 + xrv + e0, m1 = x1 + xrv + e1;
        float m2 = x2 + xrv + e2, m3 = x3 + xrv + e3;
        m0 = (m0 > 0.f) ? m0 : 0.2f * m0;  m1 = (m1 > 0.f) ? m1 : 0.2f * m1;
        m2 = (m2 > 0.f) ? m2 : 0.2f * m2;  m3 = (m3 > 0.f) ? m3 : 0.2f * m3;
        float q0 = m0 * a0, q1 = m1 * a0, q2 = m2 * a0, q3 = m3 * a0;
#pragma unroll
        for (int off = 1; off <= 32; off <<= 1) {
            q0 += __shfl_xor(q0, off, 64);
            q1 += __shfl_xor(q1, off, 64);
            q2 += __shfl_xor(q2, off, 64);
            q3 += __shfl_xor(q3, off, 64);
        }
        float nm = fmaxf(fmaxf(fmaxf(q0, q1), fmaxf(q2, q3)), m);
        float r  = __expf(m - nm);
        float w0 = __expf(q0 - nm), w1 = __expf(q1 - nm);
        float w2 = __expf(q2 - nm), w3 = __expf(q3 - nm);
        s = fmaf(s, r, (w0 + w1) + (w2 + w3));
        acc = fmaf(acc, r, fmaf(w0, x0, fmaf(w1, x1, fmaf(w2, x2, w3 * x3))));
        m = nm;
    }
    for (; i < end; ++i) {
        int2 pr = pairs[i];
        const float* er = ea + (size_t)pr.y * 16;
        float xv = xl[(size_t)pr.x * 64 + lane];
        float ec = 0.f;
#pragma unroll
        for (int k = 0; k < 16; ++k) ec = fmaf(er[k], w[k], ec);
        float mm = xv + xrv + ec;
        mm = (mm > 0.f) ? mm : 0.2f * mm;
        float p = mm * a0;
#pragma unroll
        for (int off = 1; off <= 32; off <<= 1) p += __shfl_xor(p, off, 64);
        float nm = fmaxf(m, p);
        float r = __expf(m - nm), ww = __expf(p - nm);
        s = fmaf(s, r, ww);
        acc = fmaf(acc, r, ww * xv);
        m = nm;
    }
    out[(size_t)d * 64 + lane] = acc / (s + 1e-16f) + bb;
}

// ---------------- batch-norm stats ----------------
template <int C>
__global__ __launch_bounds__(256) void bn_stats_kernel(const float* __restrict__ h, float* __restrict__ stats) {
    const int SUB = 256 / C;
    int t = threadIdx.x;
    int c = t & (C - 1);
    int rs = t / C;
    int r0 = blockIdx.x * 512;
    int r1 = min(NN, r0 + 512);
    float s = 0.f, s2 = 0.f;
    for (int r = r0 + rs; r < r1; r += SUB) {
        float v = h[(size_t)r * C + c];
        s += v; s2 = fmaf(v, v, s2);
    }
    __shared__ float ls[256], ls2[256];
    ls[t] = s; ls2[t] = s2;
    __syncthreads();
    if (rs == 0) {
        for (int j = 1; j < SUB; ++j) { s += ls[j * C + c]; s2 += ls2[j * C + c]; }
        atomicAdd(&stats[c], s);
        atomicAdd(&stats[C + c], s2);
    }
}

// ---------------- BN apply + skip + ELU ----------------
template <int C>
__global__ __launch_bounds__(256) void bn_apply_kernel(
    const float* __restrict__ h, const float* __restrict__ xp,
    const float* __restrict__ stats, const float* __restrict__ g,
    const float* __restrict__ b, float* __restrict__ outp)
{
    int i = blockIdx.x * 256 + threadIdx.x;
    if (i >= NN * C) return;
    int c = i & (C - 1);
    float mu = stats[c] * (1.f / NN);
    float var = stats[C + c] * (1.f / NN) - mu * mu;
    float sc = rsqrtf(var + 1e-5f) * g[c];
    float v = (h[i] - mu) * sc + b[c] + xp[i];
    outp[i] = (v > 0.f) ? v : expm1f(v);
}

// ---------------- per-graph mean/max pooling ----------------
__global__ __launch_bounds__(256) void pool_kernel(
    const float* __restrict__ h2, const int* __restrict__ batch, float* __restrict__ pooled)
{
    int g = blockIdx.x;
    int t = threadIdx.x;
    int lane = t & 63, w = t >> 6;
    int lo = 0, hi = NN;
    while (lo < hi) { int mid = (lo + hi) >> 1; if (batch[mid] < g) lo = mid + 1; else hi = mid; }
    int s0 = lo;
    hi = NN;
    while (lo < hi) { int mid = (lo + hi) >> 1; if (batch[mid] < g + 1) lo = mid + 1; else hi = mid; }
    int e0 = lo;
    float sum = 0.f, mx = -INFINITY;
    for (int r = s0 + w; r < e0; r += 4) {
        float v = h2[(size_t)r * 64 + lane];
        sum += v; mx = fmaxf(mx, v);
    }
    __shared__ float lsum[256], lmax[256];
    lsum[t] = sum; lmax[t] = mx;
    __syncthreads();
    if (w == 0) {
        for (int j = 1; j < 4; ++j) { sum += lsum[j * 64 + lane]; mx = fmaxf(mx, lmax[j * 64 + lane]); }
        float cnt = (float)(e0 - s0);
        pooled[g * 128 + lane] = sum / fmaxf(cnt, 1.f);
        pooled[g * 128 + 64 + lane] = mx;
    }
}

// ---------------- classifier ----------------
__global__ void classifier_kernel(const float* __restrict__ pooled, const float* __restrict__ w,
                                  const float* __restrict__ b, float* __restrict__ outp)
{
    int t = threadIdx.x;
    if (t < 100) {
        int g = t >> 1, c = t & 1;
        float acc = b[c];
        for (int k = 0; k < 128; ++k) acc = fmaf(pooled[g * 128 + k], w[k * 2 + c], acc);
        outp[t] = acc;
    }
}

extern "C" void kernel_launch(void* const* d_in, const int* in_sizes, int n_in,
                              void* d_out, int out_size, void* d_ws, size_t ws_size,
                              hipStream_t stream)
{
    const float* x       = (const float*)d_in[0];
    const int*   ei      = (const int*)d_in[1];
    const float* ea      = (const float*)d_in[2];
    const int*   batch   = (const int*)d_in[3];
    const float* skip1_w = (const float*)d_in[4];
    const float* skip1_b = (const float*)d_in[5];
    const float* c1_wl   = (const float*)d_in[6];
    const float* c1_bl   = (const float*)d_in[7];
    const float* c1_wr   = (const float*)d_in[8];
    const float* c1_br   = (const float*)d_in[9];
    const float* c1_we   = (const float*)d_in[10];
    const float* c1_att  = (const float*)d_in[11];
    const float* c1_bias = (const float*)d_in[12];
    const float* bn1_g   = (const float*)d_in[13];
    const float* bn1_b   = (const float*)d_in[14];
    const float* skip2_w = (const float*)d_in[15];
    const float* skip2_b = (const float*)d_in[16];
    const float* c2_wl   = (const float*)d_in[17];
    const float* c2_bl   = (const float*)d_in[18];
    const float* c2_wr   = (const float*)d_in[19];
    const float* c2_br   = (const float*)d_in[20];
    const float* c2_we   = (const float*)d_in[21];
    const float* c2_att  = (const float*)d_in[22];
    const float* c2_bias = (const float*)d_in[23];
    const float* bn2_g   = (const float*)d_in[24];
    const float* bn2_b   = (const float*)d_in[25];
    const float* cls_w   = (const float*)d_in[26];
    const float* cls_b   = (const float*)d_in[27];
    float* outp = (float*)d_out;

    float* ws = (float*)d_ws;
    size_t o = 0;
    float* A   = ws + o; o += 6400000;   // xl1 ; later xl2 + xr2
    float* B   = ws + o; o += 6400000;   // xr1 ; later h
    float* Cb  = ws + o; o += 6400000;   // xp1 ; later xp2 + h2
    float* D   = ws + o; o += 6400000;   // h1  ; later h2 pre-BN
    int2*  PAIRS = (int2*)(ws + o); o += 1600000;
    u32*   COUNTS  = (u32*)(ws + o); o += 50000;
    u32*   CURSORS = (u32*)(ws + o); o += 50000;
    float* STATS1  = ws + o; o += 256;
    float* STATS2  = ws + o; o += 128;
    int*   ROWPTR  = (int*)(ws + o); o += 50016;
    u32*   BSUMS   = (u32*)(ws + o); o += 64;
    float* POOLED  = ws + o; o += 6400;

    float* xl2 = A;
    float* xr2 = A + 3200000;
    float* xp2 = Cb;
    float* h2  = Cb + 3200000;

    zero_u32_kernel<<<(100384 + 255) / 256, 256, 0, stream>>>(COUNTS, 100384);

    count_edges_kernel<<<(NE + 255) / 256, 256, 0, stream>>>(ei, COUNTS);
    scan_part1_kernel<<<49, 256, 0, stream>>>(COUNTS, BSUMS);
    scan_offsets_kernel<<<1, 64, 0, stream>>>(BSUMS, 49);
    scan_final_kernel<<<49, 256, 0, stream>>>(COUNTS, BSUMS, ROWPTR);
    scatter_edges_kernel<<<(NE + 255) / 256, 256, 0, stream>>>(ei, ROWPTR, CURSORS, PAIRS);

    // ---- layer 1 ----
    gemm_multi_kernel<<<782, 256, 0, stream>>>(x,
        c1_wl, c1_bl, A,
        c1_wr, c1_br, B,
        skip1_w, skip1_b, Cb,
        NN, 128);
    gat1_fused_kernel<<<NN / 4, 256, 0, stream>>>(A, B, ea, PAIRS, ROWPTR, c1_we, c1_att, c1_bias, D);
    bn_stats_kernel<128><<<98, 256, 0, stream>>>(D, STATS1);
    bn_apply_kernel<128><<<(NN * 128 + 255) / 256, 256, 0, stream>>>(D, Cb, STATS1, bn1_g, bn1_b, B);

    // ---- layer 2 ----
    gemm_multi_kernel<<<782, 256, 0, stream>>>(B,
        c2_wl, c2_bl, xl2,
        c2_wr, c2_br, xr2,
        skip2_w, skip2_b, xp2,
        NN, 64);
    gat2_fused_kernel<<<NN / 4, 256, 0, stream>>>(xl2, xr2, ea, PAIRS, ROWPTR, c2_we, c2_att, c2_bias, D);
    bn_stats_kernel<64><<<98, 256, 0, stream>>>(D, STATS2);
    bn_apply_kernel<64><<<(NN * 64 + 255) / 256, 256, 0, stream>>>(D, xp2, STATS2, bn2_g, bn2_b, h2);

    // ---- pool + classify ----
    pool_kernel<<<GG, 256, 0, stream>>>(h2, batch, POOLED);
    classifier_kernel<<<1, 128, 0, stream>>>(POOLED, cls_w, cls_b, outp);
}